// Round 1
// 276.138 us; speedup vs baseline: 1.0459x; 1.0459x over previous
//
#include <hip/hip_runtime.h>
#include <cstdint>
#include <cstddef>

typedef _Float16 f16;
typedef _Float16 f16x8 __attribute__((ext_vector_type(8)));
typedef _Float16 f16x4 __attribute__((ext_vector_type(4)));
typedef float f32x4 __attribute__((ext_vector_type(4)));

// Problem constants
#define BATCH 16
#define INC   128
#define OUTC  128
#define HH    64
#define WW    64
#define HP    66   // padded
#define WP    66
#define ZDIM  256

// Workspace layout (f16 elements)
#define XP_ELEMS (16ull * HP * WP * INC)            // 8,921,088 f16
#define WA_ELEMS (16ull * 9 * OUTC * INC)           // 2,359,296 f16

// global -> LDS direct copy, 16B per lane. LDS dest layout must be linear in
// lane order (base + lane*16) -- all uses below satisfy this.
#define GLOAD16(g, l)                                                     \
    __builtin_amdgcn_global_load_lds(                                     \
        (const __attribute__((address_space(1))) void*)(g),               \
        (__attribute__((address_space(3))) void*)(l), 16, 0, 0)

__device__ __forceinline__ f16x8 cvt8(float4 a, float4 b) {
    f16x8 r;
    r[0] = (f16)a.x; r[1] = (f16)a.y; r[2] = (f16)a.z; r[3] = (f16)a.w;
    r[4] = (f16)b.x; r[5] = (f16)b.y; r[6] = (f16)b.z; r[7] = (f16)b.w;
    return r;
}

// ---------------------------------------------------------------------------
// Fused prep kernel. The three jobs are mutually independent (disjoint
// outputs), so they run concurrently inside one dispatch:
//   blocks [0, 2304)     : wgen  (per-sample weights, MFMA GEMM) -- long pole
//   blocks [2304, 6400)  : xprep (NCHW fp32 -> padded NHWC f16)
//   blocks [6400, 6660)  : zero xp borders
// ---------------------------------------------------------------------------
__global__ __launch_bounds__(256) void prep(const float* __restrict__ x,
                                            const float* __restrict__ z,
                                            const float* __restrict__ base_w,
                                            const float* __restrict__ head_w,
                                            const float* __restrict__ head_b,
                                            f16* __restrict__ xp,
                                            f16* __restrict__ wA) {
    __shared__ float tile[32 * 65];   // xprep transpose staging (8.3 KB)
    int blk = blockIdx.x;
    int tid = threadIdx.x;

    if (blk < 2304) {
        // ---------------- wgen ----------------
        // Wave tile: 16 GEMM rows = 16 consecutive ic at fixed (oc,r), 16
        // cols = batches. Rolling A prefetch depth 2.
        int lane = tid & 63;
        int wv   = tid >> 6;
        int r16  = lane & 15;
        int quad = lane >> 4;
        int tl   = blk * 4 + wv;                 // 0..9215
        int icb  = tl & 7;                       // ic block of 16
        int oc   = (tl >> 3) & 127;
        int r    = tl >> 10;                     // 0..8
        int base = (oc * 128 + icb * 16) * 9 + r;
        int myrow = base + 9 * r16;

        const float4* zrow = (const float4*)(z + (size_t)r16 * ZDIM);
        f16x8 bfr[8];
#pragma unroll
        for (int s = 0; s < 8; ++s)
            bfr[s] = cvt8(zrow[s * 8 + quad * 2], zrow[s * 8 + quad * 2 + 1]);

        const float4* hw = (const float4*)(head_w + (size_t)myrow * ZDIM);
        float4 a[3][2];
        a[0][0] = hw[quad * 2];     a[0][1] = hw[quad * 2 + 1];
        a[1][0] = hw[8 + quad * 2]; a[1][1] = hw[8 + quad * 2 + 1];
        f32x4 acc = {0.f, 0.f, 0.f, 0.f};
#pragma unroll
        for (int s = 0; s < 8; ++s) {
            if (s + 2 < 8) {
                a[(s + 2) % 3][0] = hw[(s + 2) * 8 + quad * 2];
                a[(s + 2) % 3][1] = hw[(s + 2) * 8 + quad * 2 + 1];
            }
            acc = __builtin_amdgcn_mfma_f32_16x16x32_f16(
                cvt8(a[s % 3][0], a[s % 3][1]), bfr[s], acc, 0, 0, 0);
        }

        f16x4 ov;
        int icl = quad * 4;
#pragma unroll
        for (int reg = 0; reg < 4; ++reg) {
            int o = base + 9 * (icl + reg);
            ov[reg] = (f16)(base_w[o] + head_b[o] + acc[reg]);
        }
        size_t idx = (((size_t)r16 * 9 + r) * OUTC + oc) * INC + icb * 16 + icl;
        *(f16x4*)(wA + idx) = ov;

    } else if (blk < 6400) {
        // ---------------- xprep ----------------
        int xb  = blk - 2304;
        int icC = xb & 3;             // 4 chunks of 32 ic
        int h   = (xb >> 2) & 63;
        int b   = xb >> 8;
        int ic0 = icC * 32;
        {
            int i = tid >> 3;         // ic 0..31
            int j = tid & 7;          // 8-float chunk
            const float4* src = (const float4*)(x + (((size_t)b * INC + ic0 + i) * HH + h) * WW) + j * 2;
            float4 v0 = src[0];
            float4 v1 = src[1];
            float* tp = tile + i * 65 + j * 8;
            tp[0] = v0.x; tp[1] = v0.y; tp[2] = v0.z; tp[3] = v0.w;
            tp[4] = v1.x; tp[5] = v1.y; tp[6] = v1.z; tp[7] = v1.w;
        }
        __syncthreads();
        {
            int w = tid >> 2;         // 0..63
            int q = tid & 3;          // which 8-ic group
            f16 o8[8];
#pragma unroll
            for (int jj = 0; jj < 8; ++jj)
                o8[jj] = (f16)tile[(q * 8 + jj) * 65 + w];
            f16* dst = xp + (((size_t)b * HP + (h + 1)) * WP + (w + 1)) * INC + ic0 + q * 8;
            *(uint4*)dst = *(uint4*)o8;
        }

    } else {
        // ---------------- zero xp borders ----------------
        unsigned i = (unsigned)(blk - 6400) * 256u + (unsigned)tid;
        unsigned b = i / 4160;
        unsigned j = i - b * 4160;
        unsigned row, wc, ic8;
        if (j < 2112) {                 // rows 0 and 65, full width
            row = (j < 1056) ? 0u : 65u;
            unsigned jj = (j < 1056) ? j : j - 1056;
            wc  = jj >> 4;
            ic8 = jj & 15;
        } else {                        // rows 1..64, cols 0 and 65
            unsigned j2 = j - 2112;
            row = 1 + (j2 >> 5);
            unsigned k = j2 & 31;
            wc  = (k < 16) ? 0u : 65u;
            ic8 = k & 15;
        }
        uint4 zv = {0u, 0u, 0u, 0u};
        *(uint4*)(xp + (((size_t)b * HP + row) * WP + wc) * INC + ic8 * 8) = zv;
    }
}

// ---------------------------------------------------------------------------
// conv: implicit GEMM, f16 MFMA 16x16x32.
// vs previous round:
//   * LDS pitch 40 -> 32 (still uniform 8-access/bank for ds_read_b128, the
//     wave64 minimum) => linear layout => global_load_lds direct staging.
//   * Weight LDS double-buffered (two distinct __shared__ arrays; parity is
//     compile-time after full unroll). STAGE(next) issued BEFORE the MFMA
//     block for the current stage, so the vmcnt(0) drain at the barrier is
//     covered by 48 MFMAs instead of fully exposed.
//   * XCD-aware block swizzle (512 % 8 == 0, bijective): blocks sharing a
//     batch (same 288 KB weight slice) land on the same XCD's L2.
// ---------------------------------------------------------------------------
__global__ __launch_bounds__(256) void conv(const f16* __restrict__ xp,
                                            const f16* __restrict__ wA,
                                            float* __restrict__ out) {
    int blk0 = blockIdx.x;                       // 512 = 16 b * 32 row-pairs
    int blk  = (blk0 & 7) * 64 + (blk0 >> 3);    // XCD swizzle (bijective)
    int b  = blk >> 5;
    int pt = blk & 31;
    int h0 = pt * 2;                             // output rows h0, h0+1

    int tid    = threadIdx.x;
    int lane   = tid & 63;
    int wv     = tid >> 6;
    int ocHalf = wv & 1;
    int pHalf  = wv >> 1;
    int m0     = ocHalf * 64;
    int row16  = lane & 15;
    int quad   = lane >> 4;

    __shared__ __align__(16) f16 ws0[3 * 128 * 32];   // [kw][oc][ic32], 24 KB
    __shared__ __align__(16) f16 ws1[3 * 128 * 32];   // double buffer
    __shared__ __align__(16) f16 xs [4 * 66 * 32];    // [row0..3][wc][ic32], 16.5 KB

    f32x4 acc[4][4];
#pragma unroll
    for (int mt = 0; mt < 4; ++mt)
#pragma unroll
        for (int nt = 0; nt < 4; ++nt)
            acc[mt][nt] = f32x4{0.f, 0.f, 0.f, 0.f};

    // stage weights for (c, kh) into wb: 1536 x 16B, linear in lds
    auto stage_w = [&](f16* wb, int c, int kh) {
#pragma unroll
        for (int i = 0; i < 6; ++i) {
            int idx  = tid + i * 256;             // 0..1535
            int kw   = idx >> 9;                  // 0..2
            int oc   = (idx >> 2) & 127;
            int part = idx & 3;
            const f16* src = wA +
                ((((size_t)b * 9 + kh * 3 + kw) * OUTC + oc) * INC + c * 32 + part * 8);
            GLOAD16(src, wb + (size_t)idx * 8);
        }
    };
    // stage x rows h0..h0+3 for ic chunk c: 1056 x 16B, linear in lds
    auto stage_x = [&](int c) {
#pragma unroll
        for (int i = 0; i < 5; ++i) {
            int idx = tid + i * 256;
            if (idx < 1056) {
                int seg  = idx >> 2;              // 0..263
                int part = idx & 3;
                int row  = seg / 66;              // 0..3
                int wc   = seg - row * 66;
                const f16* src = xp +
                    ((((size_t)b * HP + h0 + row) * WP + wc) * INC + c * 32 + part * 8);
                GLOAD16(src, xs + (size_t)idx * 8);
            }
        }
    };

    // prologue
    stage_x(0);
    stage_w(ws0, 0, 0);
    __syncthreads();

#pragma unroll
    for (int c = 0; c < 4; ++c) {
#pragma unroll
        for (int kh = 0; kh < 3; ++kh) {
            const int s = c * 3 + kh;
            f16* cur = (s & 1) ? ws1 : ws0;
            if (s < 11) {
                const int sn = s + 1;
                f16* nxt = (sn & 1) ? ws1 : ws0;
                stage_w(nxt, sn / 3, sn % 3);     // issue-before-compute
            }
#pragma unroll
            for (int kw = 0; kw < 3; ++kw) {
                f16x8 afr[4], bfr[4];
#pragma unroll
                for (int mt = 0; mt < 4; ++mt)
                    afr[mt] = *(const f16x8*)(cur +
                        ((size_t)(kw * 128 + m0 + mt * 16 + row16) * 32 + quad * 8));
#pragma unroll
                for (int nt = 0; nt < 4; ++nt)
                    bfr[nt] = *(const f16x8*)(xs +
                        ((size_t)((kh + pHalf) * 66 + nt * 16 + row16 + kw) * 32 + quad * 8));
#pragma unroll
                for (int mt = 0; mt < 4; ++mt)
#pragma unroll
                    for (int nt = 0; nt < 4; ++nt)
                        acc[mt][nt] = __builtin_amdgcn_mfma_f32_16x16x32_f16(
                            afr[mt], bfr[nt], acc[mt][nt], 0, 0, 0);
            }
            __syncthreads();                      // drains next-buf staging under MFMA cover
            if (kh == 2 && c < 3) {               // xs is single-buffered: restage at c boundary
                stage_x(c + 1);
                __syncthreads();
            }
        }
    }

    // epilogue: D row = oc (quad*4+reg), col = pixel-in-row (lane&15)
    int hrow = h0 + pHalf;
#pragma unroll
    for (int mt = 0; mt < 4; ++mt)
#pragma unroll
        for (int nt = 0; nt < 4; ++nt) {
            int wc = nt * 16 + row16;
#pragma unroll
            for (int reg = 0; reg < 4; ++reg) {
                int oc = m0 + mt * 16 + quad * 4 + reg;
                out[(((size_t)b * OUTC + oc) * HH + hrow) * WW + wc] = acc[mt][nt][reg];
            }
        }
}

// ---------------------------------------------------------------------------
extern "C" void kernel_launch(void* const* d_in, const int* in_sizes, int n_in,
                              void* d_out, int out_size, void* d_ws, size_t ws_size,
                              hipStream_t stream) {
    const float* x      = (const float*)d_in[0];
    const float* z      = (const float*)d_in[1];
    const float* base_w = (const float*)d_in[2];
    const float* head_w = (const float*)d_in[3];
    const float* head_b = (const float*)d_in[4];
    float* out = (float*)d_out;

    f16* xp  = (f16*)d_ws;              // XP_ELEMS f16
    f16* wAp = xp + XP_ELEMS;           // WA_ELEMS f16

    // fused prep: 2304 wgen + 4096 xprep + 260 border-zero blocks
    prep<<<6660, 256, 0, stream>>>(x, z, base_w, head_w, head_b, xp, wAp);
    conv<<<512, 256, 0, stream>>>(xp, wAp, out);
}